// Round 1
// baseline (2524.324 us; speedup 1.0000x reference)
//
#include <hip/hip_runtime.h>
#include <stdint.h>

#define N_TOK 8192
#define DMODEL 2048
#define VOCAB 50257
#define VPAD 50304            // 393 * 128
#define IGNORE_INDEX (-100)

#define BM 128
#define BN 128
#define BK 32
#define N_RT (N_TOK / BM)     // 64 row tiles
#define N_VT (VPAD / BN)      // 393 vocab tiles

typedef __attribute__((ext_vector_type(8))) short short8;
typedef __attribute__((ext_vector_type(4))) float float4v;

__device__ __forceinline__ unsigned short f32_to_bf16(float f) {
  union { float f; uint32_t u; } v; v.f = f;
  uint32_t u = v.u;
  uint32_t r = u + 0x7fffu + ((u >> 16) & 1u);   // round-to-nearest-even
  return (unsigned short)(r >> 16);
}

__device__ __forceinline__ void gl2lds16(const unsigned short* g, unsigned short* l) {
  __builtin_amdgcn_global_load_lds(
      (const __attribute__((address_space(1))) void*)g,
      (__attribute__((address_space(3))) void*)l,
      16, 0, 0);
}

// ---- conversion kernels -------------------------------------------------

__global__ void convert_c_kernel(const float* __restrict__ c,
                                 unsigned short* __restrict__ cbf) {
  size_t idx4 = (size_t)blockIdx.x * 256 + threadIdx.x;   // 4 elems per thread
  size_t base = idx4 * 4;
  ushort4 o;
  if (base < (size_t)VOCAB * DMODEL) {
    const float4* c4 = (const float4*)c;
    float4 f = c4[idx4];
    o.x = f32_to_bf16(f.x); o.y = f32_to_bf16(f.y);
    o.z = f32_to_bf16(f.z); o.w = f32_to_bf16(f.w);
  } else {
    o.x = 0; o.y = 0; o.z = 0; o.w = 0;                   // pad rows -> 0
  }
  ((ushort4*)cbf)[idx4] = o;
}

__global__ void convert_e_kernel(const float* __restrict__ e,
                                 unsigned short* __restrict__ ebf) {
  size_t idx4 = (size_t)blockIdx.x * 256 + threadIdx.x;
  const float4* e4 = (const float4*)e;
  float4 f = e4[idx4];
  ushort4 o;
  o.x = f32_to_bf16(f.x); o.y = f32_to_bf16(f.y);
  o.z = f32_to_bf16(f.z); o.w = f32_to_bf16(f.w);
  ((ushort4*)ebf)[idx4] = o;
}

__global__ void init_kernel(float* __restrict__ p) {   // zero S and TGT
  int idx = blockIdx.x * 256 + threadIdx.x;
  if (idx < 2 * N_TOK) p[idx] = 0.0f;
}

// ---- fused GEMM + online exp-sum ---------------------------------------

__global__ void __launch_bounds__(256) cce_gemm_kernel(
    const unsigned short* __restrict__ ebf,
    const unsigned short* __restrict__ cbf,
    const int* __restrict__ targets,
    float* __restrict__ S,
    float* __restrict__ TGT) {
  __shared__ unsigned short sA[BM * BK];   // 8 KB
  __shared__ unsigned short sB[BN * BK];   // 8 KB
  __shared__ int sTgt[BM];

  const int bx  = blockIdx.x;
  const int rt  = bx & (N_RT - 1);   // consecutive blocks share vocab tile
  const int vt  = bx >> 6;
  const int row0 = rt * BM;
  const int col0 = vt * BN;

  const int tid  = threadIdx.x;
  const int w    = tid >> 6;
  const int lane = tid & 63;

  if (tid < BM) sTgt[tid] = targets[row0 + tid];

  // ---- staging addresses: chunk ci = it*256 + tid; row = ci>>2, colchunk = ci&3
  const unsigned short* gA0 = ebf + (size_t)(row0 + (tid >> 2)) * DMODEL + (tid & 3) * 8;
  const unsigned short* gA1 = gA0 + (size_t)64 * DMODEL;
  const unsigned short* gB0 = cbf + (size_t)(col0 + (tid >> 2)) * DMODEL + (tid & 3) * 8;
  const unsigned short* gB1 = gB0 + (size_t)64 * DMODEL;
  // wave-uniform LDS bases (16B per lane appended by HW)
  unsigned short* lA0 = &sA[w * 512];
  unsigned short* lA1 = &sA[2048 + w * 512];
  unsigned short* lB0 = &sB[w * 512];
  unsigned short* lB1 = &sB[2048 + w * 512];

  const int m15 = lane & 15;
  const int q   = lane >> 4;
  const int rw0 = (w >> 1) * 64;
  const int cw0 = (w & 1) * 64;

  float4v acc[4][4];
#pragma unroll
  for (int i = 0; i < 4; i++)
#pragma unroll
    for (int j = 0; j < 4; j++) acc[i][j] = (float4v)0.0f;

  for (int kt = 0; kt < DMODEL / BK; ++kt) {
    const int ko = kt * BK;
    gl2lds16(gA0 + ko, lA0);
    gl2lds16(gA1 + ko, lA1);
    gl2lds16(gB0 + ko, lB0);
    gl2lds16(gB1 + ko, lB1);
    __syncthreads();

    short8 a[4], b[4];
#pragma unroll
    for (int i = 0; i < 4; i++)
      a[i] = *(const short8*)&sA[(rw0 + i * 16 + m15) * BK + q * 8];
#pragma unroll
    for (int j = 0; j < 4; j++)
      b[j] = *(const short8*)&sB[(cw0 + j * 16 + m15) * BK + q * 8];

#pragma unroll
    for (int i = 0; i < 4; i++)
#pragma unroll
      for (int j = 0; j < 4; j++)
        acc[i][j] = __builtin_amdgcn_mfma_f32_16x16x32_bf16(a[i], b[j], acc[i][j], 0, 0, 0);

    __syncthreads();
  }

  // ---- epilogue: per-row sum(exp(logit)) + target-logit pick
  // C/D layout: row = q*4 + t (within 16), col = m15
#pragma unroll
  for (int i = 0; i < 4; i++) {
#pragma unroll
    for (int t = 0; t < 4; t++) {
      const int rloc = rw0 + i * 16 + q * 4 + t;
      const int trg  = sTgt[rloc];
      float s = 0.0f;
#pragma unroll
      for (int j = 0; j < 4; j++) {
        const int col = col0 + cw0 + j * 16 + m15;
        const float v = acc[i][j][t];
        if (col < VOCAB) s += __expf(v);
        if (col == trg) TGT[row0 + rloc] = v;
      }
#pragma unroll
      for (int o = 1; o < 16; o <<= 1) s += __shfl_xor(s, o, 64);
      if (m15 == 0) atomicAdd(&S[row0 + rloc], s);
    }
  }
}

// ---- finalize -----------------------------------------------------------

__global__ void finalize_kernel(const float* __restrict__ S,
                                const float* __restrict__ TGT,
                                const int* __restrict__ targets,
                                float* __restrict__ out) {
  __shared__ float rs[256];
  __shared__ int   rc[256];
  const int tid = threadIdx.x;
  float acc = 0.0f;
  int cnt = 0;
  for (int r = tid; r < N_TOK; r += 256) {
    const int t = targets[r];
    if (t != IGNORE_INDEX) {
      acc += logf(S[r]) - TGT[r];
      cnt++;
    }
  }
  rs[tid] = acc; rc[tid] = cnt;
  __syncthreads();
  for (int o = 128; o > 0; o >>= 1) {
    if (tid < o) { rs[tid] += rs[tid + o]; rc[tid] += rc[tid + o]; }
    __syncthreads();
  }
  if (tid == 0) out[0] = rs[0] / (float)(rc[0] > 0 ? rc[0] : 1);
}

// ---- launch -------------------------------------------------------------

extern "C" void kernel_launch(void* const* d_in, const int* in_sizes, int n_in,
                              void* d_out, int out_size, void* d_ws, size_t ws_size,
                              hipStream_t stream) {
  const float* e       = (const float*)d_in[0];
  const float* c       = (const float*)d_in[1];
  const int*   targets = (const int*)d_in[2];
  float* out = (float*)d_out;

  char* ws = (char*)d_ws;
  unsigned short* cbf = (unsigned short*)ws;                                   // VPAD*D bf16
  unsigned short* ebf = (unsigned short*)(ws + (size_t)VPAD * DMODEL * 2);     // N_TOK*D bf16
  float* S   = (float*)(ws + (size_t)VPAD * DMODEL * 2 + (size_t)N_TOK * DMODEL * 2);
  float* TGT = S + N_TOK;

  // c: VPAD*DMODEL/4 chunks of 4 floats
  convert_c_kernel<<<dim3((unsigned)((size_t)VPAD * DMODEL / 4 / 256)), dim3(256), 0, stream>>>(c, cbf);
  convert_e_kernel<<<dim3((unsigned)((size_t)N_TOK * DMODEL / 4 / 256)), dim3(256), 0, stream>>>(e, ebf);
  init_kernel<<<dim3((2 * N_TOK + 255) / 256), dim3(256), 0, stream>>>(S);

  cce_gemm_kernel<<<dim3(N_RT * N_VT), dim3(256), 0, stream>>>(ebf, cbf, targets, S, TGT);

  finalize_kernel<<<dim3(1), dim3(256), 0, stream>>>(S, TGT, targets, out);
}